// Round 12
// baseline (35.835 us; speedup 1.0000x reference)
//
#include <hip/hip_runtime.h>

#define EPSV 2.220446049250313e-16f
#define C3F  (-0.09016844005555896f)   // -log2(e)/16
#define SSCL 0.1201122408786449f       // sqrt(log2(e)/100); (SSCL*dI)^2 = dI^2*log2(e)/100
#define EPSS (EPSV * SSCL)

typedef float f2 __attribute__((ext_vector_type(2)));
typedef float f4 __attribute__((ext_vector_type(4)));

// Half-space (pair-symmetry) formulation, R9-verified algebra:
//   acc_k(p) = sum_{o in H} w(p,p+o) * Ppad_k(p+o)      (125 in-ball offsets)
//   A_k = sum_p [ 2*P_k(p)*acc_k(p) + P_k(p)^2 ]
//   V_k = sum_p [ P_k(p)*(W(p) + e(p)*S(p) + 1) + acc_k(p) ]
// Grid: (oz,b,d) = 4*8*32 = 1024 blocks, 256 threads, 4 voxels/thread.
// R12: OZ is a template parameter -> ALL ball/lex guards and dist constants
// fold at compile time; the hot loop is a straight-line FMA/exp stream.

template<int OZ>
__device__ __forceinline__ void ncut_body(const float* __restrict__ batch,
                                          const float* __restrict__ preds,
                                          float* __restrict__ wsA,
                                          float* __restrict__ wsV,
                                          float* sAll, float (*redBuf)[12],
                                          int bx) {
    constexpr int LS = 38;             // LDS row stride (floats)
    constexpr int PLANE = 38 * LS;     // 1444 floats per padded slice
    constexpr int CZZ = OZ * OZ;
    constexpr float GZ = (float)CZZ * C3F;

    const int tid = threadIdx.x;
    const int b   = (bx >> 5) & 7;     // batch
    const int d   = bx & 31;           // center z-slice

    const int z   = d + OZ;            // partner slice (never <0)
    const bool zok = (z < 32);

    // ---- init planes to pad value (7*1444/4 = 2527 f4) ----
    {
        f4* a4 = (f4*)sAll;
        const f4 bpad = {EPSS, EPSS, EPSS, EPSS};
        const f4 ppad = {EPSV, EPSV, EPSV, EPSV};
        for (int i = tid; i < 2527; i += 256) a4[i] = (i < 361) ? bpad : ppad;
    }
    __syncthreads();

    // ---- copy interiors: coalesced f4 loads ----
    const int hh = tid >> 3;           // 0..31
    const int j4 = (tid & 7) << 2;     // 0,4,...,28
    if (zok) {
        const float* bsrc = batch + ((size_t)b * 32 + z) * 1024 + hh * 32 + j4;
        const float* psrc = preds + ((size_t)b * 6 * 32 + z) * 1024 + hh * 32 + j4;
        {
            f4 v = *(const f4*)bsrc;
            v *= SSCL;
            float* dst = sAll + (hh + 3) * LS + (j4 + 3);
            dst[0] = v.x; dst[1] = v.y; dst[2] = v.z; dst[3] = v.w;
        }
        #pragma unroll
        for (int p = 0; p < 6; ++p) {
            f4 v = *(const f4*)(psrc + (size_t)p * 32768);
            float* dst = sAll + (p + 1) * PLANE + (hh + 3) * LS + (j4 + 3);
            dst[0] = v.x; dst[1] = v.y; dst[2] = v.z; dst[3] = v.w;
        }
    }

    const int h  = hh;                 // row
    const int v0 = j4;                 // voxel start
    f4 Ip = *(const f4*)&batch[((size_t)b * 32 + d) * 1024 + h * 32 + v0];
    Ip *= SSCL;

    __syncthreads();

    f4 wsum = {};
    f4 acc[6] = {};

    #pragma unroll
    for (int dy = 0; dy < 7; ++dy) {
        constexpr int _d = 0;  (void)_d;
        const int oy  = dy - 3;
        const int cyy = oy * oy;                       // compile-time
        if (CZZ + cyy >= 16) continue;                 // folds
        if (OZ == 0 && oy < 0) continue;               // folds

        const int rowOff = (h + dy) * LS + v0;         // even -> 8B aligned
        const f2* base = (const f2*)(sAll + rowOff);
        constexpr int PL2 = PLANE / 2;                 // f2 stride per plane

        // issue bseg AND pseg(k=0) together: weight chain hides pseg(0) latency
        f2 tb0 = base[0], tb1 = base[1], tb2 = base[2], tb3 = base[3], tb4 = base[4];
        f2 c0 = base[PL2 + 0], c1 = base[PL2 + 1], c2 = base[PL2 + 2],
           c3 = base[PL2 + 3], c4 = base[PL2 + 4];

        float bseg[10] = {tb0.x, tb0.y, tb1.x, tb1.y, tb2.x, tb2.y, tb3.x, tb3.y, tb4.x, tb4.y};

        f4 wv[7] = {};
        #pragma unroll
        for (int dx = 0; dx < 7; ++dx) {
            const int ox  = dx - 3;
            const int cxx = ox * ox;                   // compile-time
            if (CZZ + cyy + cxx < 16 && !(OZ == 0 && oy == 0 && ox <= 0)) {  // folds
                constexpr float _gdummy = 0.f; (void)_gdummy;
                const float g = GZ + (float)(cyy + cxx) * C3F;               // literal
                f4 bv = {bseg[dx], bseg[dx + 1], bseg[dx + 2], bseg[dx + 3]};
                f4 dI = Ip - bv;
                f4 t  = (f4){g, g, g, g} - dI * dI;
                f4 w;
                w.x = __builtin_amdgcn_exp2f(t.x);
                w.y = __builtin_amdgcn_exp2f(t.y);
                w.z = __builtin_amdgcn_exp2f(t.z);
                w.w = __builtin_amdgcn_exp2f(t.w);
                wv[dx] = w;
                wsum += w;
            }
        }

        // k-loop, 2-stage pipelined: prefetch pseg(k+1) before FMA-ing pseg(k)
        #pragma unroll
        for (int k = 0; k < 6; ++k) {
            f2 n0, n1, n2, n3, n4;
            if (k < 5) {
                const f2* nb = base + (size_t)(k + 2) * PL2;
                n0 = nb[0]; n1 = nb[1]; n2 = nb[2]; n3 = nb[3]; n4 = nb[4];
            }
            float pseg[10] = {c0.x, c0.y, c1.x, c1.y, c2.x, c2.y, c3.x, c3.y, c4.x, c4.y};
            f4 a = acc[k];
            #pragma unroll
            for (int dx = 0; dx < 7; ++dx) {
                const int ox  = dx - 3;
                const int cxx = ox * ox;
                if (CZZ + cyy + cxx < 16 && !(OZ == 0 && oy == 0 && ox <= 0))  // folds
                    a += wv[dx] * (f4){pseg[dx], pseg[dx + 1], pseg[dx + 2], pseg[dx + 3]};
            }
            acc[k] = a;
            if (k < 5) { c0 = n0; c1 = n1; c2 = n2; c3 = n3; c4 = n4; }
        }
    }

    // ---- reverse-direction pad correction: S(p) = sum dist over o in H with p-o outside grid ----
    f4 S = {};
    if ((d < OZ) || (h < 3) || (h > 28) || (v0 == 0) || (v0 == 28)) {
        #pragma unroll
        for (int oy = -3; oy <= 3; ++oy) {
            #pragma unroll
            for (int ox = -3; ox <= 3; ++ox) {
                const int d2c = oy * oy + ox * ox;
                if (CZZ + d2c >= 16) continue;                               // folds
                if (OZ == 0 && (oy < 0 || (oy == 0 && ox <= 0))) continue;   // folds
                const float dist = __builtin_exp2f((float)(CZZ + d2c) * C3F); // literal
                const bool sc = (d < OZ) || (h < oy) || (h > 31 + oy);
                #pragma unroll
                for (int j = 0; j < 4; ++j) {
                    const int xj = v0 + j;
                    bool m = sc;
                    if (ox > 0) m = m || (xj < ox);        // folds unless ox>0
                    if (ox < 0) m = m || (xj > 31 + ox);   // folds unless ox<0
                    S[j] += m ? dist : 0.0f;
                }
            }
        }
    }
    // e(p) = exp2(-(sI - s*eps)^2); fold correction into wsum before the center dot
    {
        f4 dIe = Ip - (f4){EPSS, EPSS, EPSS, EPSS};
        f4 e4;
        e4.x = __builtin_amdgcn_exp2f(-dIe.x * dIe.x);
        e4.y = __builtin_amdgcn_exp2f(-dIe.y * dIe.y);
        e4.z = __builtin_amdgcn_exp2f(-dIe.z * dIe.z);
        e4.w = __builtin_amdgcn_exp2f(-dIe.w * dIe.w);
        wsum += e4 * S;
    }

    // ---- epilogue: per-class partials ----
    float pA[6], pV[6];
    #pragma unroll
    for (int k = 0; k < 6; ++k) {
        const size_t pc = (((size_t)b * 6 + k) * 32 + d) * 1024 + h * 32 + v0;
        f4 pcv = *(const f4*)&preds[pc];
        float dA = acc[k].x * pcv.x + acc[k].y * pcv.y + acc[k].z * pcv.z + acc[k].w * pcv.w;
        float hA = acc[k].x + acc[k].y + acc[k].z + acc[k].w;
        float dV = wsum.x * pcv.x + wsum.y * pcv.y + wsum.z * pcv.z + wsum.w * pcv.w;
        pA[k] = 2.0f * dA;
        pV[k] = dV + hA;
        if (OZ == 0) {   // o=0 term: A += P^2, V += P (once per (b,d)) — folds
            pA[k] += pcv.x * pcv.x + pcv.y * pcv.y + pcv.z * pcv.z + pcv.w * pcv.w;
            pV[k] += pcv.x + pcv.y + pcv.z + pcv.w;
        }
    }

    // wave reduction (64 lanes)
    #pragma unroll
    for (int k = 0; k < 6; ++k) {
        #pragma unroll
        for (int off = 32; off > 0; off >>= 1) {
            pA[k] += __shfl_down(pA[k], off);
            pV[k] += __shfl_down(pV[k], off);
        }
    }
    const int lane = tid & 63, wave = tid >> 6;
    if (lane == 0) {
        #pragma unroll
        for (int k = 0; k < 6; ++k) {
            redBuf[wave][k]     = pA[k];
            redBuf[wave][6 + k] = pV[k];
        }
    }
    __syncthreads();
    if (tid < 12) {
        float s = redBuf[0][tid] + redBuf[1][tid] + redBuf[2][tid] + redBuf[3][tid];
        if (tid < 6) wsA[bx * 6 + tid] = s;
        else         wsV[bx * 6 + (tid - 6)] = s;
    }
}

__global__ __launch_bounds__(256) void ncut_main(const float* __restrict__ batch,
                                                 const float* __restrict__ preds,
                                                 float* __restrict__ wsA,
                                                 float* __restrict__ wsV) {
    constexpr int PLANE = 38 * 38;
    __shared__ float sAll[7 * PLANE];
    __shared__ float redBuf[4][12];

    const int bx = blockIdx.x;
    const int oz = bx >> 8;            // 0..3 (wave-uniform, branched ONCE)
    if      (oz == 0) ncut_body<0>(batch, preds, wsA, wsV, sAll, redBuf, bx);
    else if (oz == 1) ncut_body<1>(batch, preds, wsA, wsV, sAll, redBuf, bx);
    else if (oz == 2) ncut_body<2>(batch, preds, wsA, wsV, sAll, redBuf, bx);
    else              ncut_body<3>(batch, preds, wsA, wsV, sAll, redBuf, bx);
}

// Reduce 128 partials per batch (4 oz * 32 d), form 6 - sum_k A_k/V_k
__global__ __launch_bounds__(128) void ncut_final(const float* __restrict__ wsA,
                                                  const float* __restrict__ wsV,
                                                  float* __restrict__ out) {
    __shared__ float redBuf[2][12];
    const int b = blockIdx.x;
    const int t = threadIdx.x;            // 0..127 = (oz, d)
    const int oz = t >> 5, dd = t & 31;
    const int bx = oz * 256 + b * 32 + dd;
    float a[6], v[6];
    #pragma unroll
    for (int k = 0; k < 6; ++k) {
        a[k] = wsA[(size_t)bx * 6 + k];
        v[k] = wsV[(size_t)bx * 6 + k];
    }
    #pragma unroll
    for (int k = 0; k < 6; ++k) {
        #pragma unroll
        for (int off = 32; off > 0; off >>= 1) {
            a[k] += __shfl_down(a[k], off);
            v[k] += __shfl_down(v[k], off);
        }
    }
    const int lane = t & 63, wave = t >> 6;
    if (lane == 0) {
        #pragma unroll
        for (int k = 0; k < 6; ++k) {
            redBuf[wave][k]     = a[k];
            redBuf[wave][6 + k] = v[k];
        }
    }
    __syncthreads();
    if (t == 0) {
        float s = 0.f;
        #pragma unroll
        for (int k = 0; k < 6; ++k) {
            float sa = redBuf[0][k] + redBuf[1][k];
            float sv = redBuf[0][6 + k] + redBuf[1][6 + k];
            s += sa / sv;
        }
        out[b] = 6.0f - s;
    }
}

extern "C" void kernel_launch(void* const* d_in, const int* in_sizes, int n_in,
                              void* d_out, int out_size, void* d_ws, size_t ws_size,
                              hipStream_t stream) {
    const float* batch = (const float*)d_in[0];   // 8*1*32^3
    const float* preds = (const float*)d_in[1];   // 8*6*32^3
    float* out = (float*)d_out;                   // 8 floats
    float* wsA = (float*)d_ws;                    // 1024*6 floats
    float* wsV = wsA + 1024 * 6;                  // 1024*6 floats

    ncut_main<<<1024, 256, 0, stream>>>(batch, preds, wsA, wsV);
    ncut_final<<<8, 128, 0, stream>>>(wsA, wsV, out);
}

// Round 13
// 31.446 us; speedup vs baseline: 1.1396x; 1.1396x over previous
//
#include <hip/hip_runtime.h>

#define EPSV 2.220446049250313e-16f
#define C3F  (-0.09016844005555896f)   // -log2(e)/16
#define SSCL 0.1201122408786449f       // sqrt(log2(e)/100)
#define EPSS (EPSV * SSCL)

typedef float f2 __attribute__((ext_vector_type(2)));
typedef float f4 __attribute__((ext_vector_type(4)));

__device__ __forceinline__ f4 exp4(f4 t) {
    f4 w;
    w.x = __builtin_amdgcn_exp2f(t.x);
    w.y = __builtin_amdgcn_exp2f(t.y);
    w.z = __builtin_amdgcn_exp2f(t.z);
    w.w = __builtin_amdgcn_exp2f(t.w);
    return w;
}

// z-fused pair-symmetric formulation (R9 algebra + slice sharing):
// Block = (b, z, pr): stages slice z once; computes centers d = z-oz for
// oz in {pr, pr+2}. Every pseg/bseg LDS read serves BOTH centers.
// Per task (b,d,oz):  acc_k(p) = sum_{o in H(oz)} w(p,p+o)*Ppad_k(p+o)
//   A_k += 2*P_k*acc_k (+P_k^2 if oz==0)
//   V_k += P_k*(W + e*S + [oz==0]) + acc_k
// S = reverse-pad dist sum + (oz==0 only) analytic forward-z-pad sum.
// Grid 512 blocks (b in bits0-2, z bits3-7, pr bit8 -> per-CU pair balance).

__global__ __launch_bounds__(256) void ncut_main(const float* __restrict__ batch,
                                                 const float* __restrict__ preds,
                                                 float* __restrict__ wsA,
                                                 float* __restrict__ wsV) {
    constexpr int LS = 38;
    constexpr int PLANE = 38 * LS;     // 1444 floats
    constexpr int PL2 = PLANE / 2;
    __shared__ float sAll[7 * PLANE];  // plane 0: scaled batch; 1..6: preds
    __shared__ float redBuf[4][24];

    const int tid = threadIdx.x;
    const int bx  = blockIdx.x;
    const int b   = bx & 7;
    const int z   = (bx >> 3) & 31;
    const int pr  = bx >> 8;           // 0: oz{0,2}, 1: oz{1,3}

    const int oz0 = pr,     oz1 = pr + 2;
    const int d0  = z - oz0, d1 = z - oz1;
    const int czz0 = oz0 * oz0, czz1 = oz1 * oz1;
    const int dl0 = d0 < 0 ? 0 : d0, dl1 = d1 < 0 ? 0 : d1;  // clamped for loads

    // ---- init pads (7*1444/4 = 2527 f4) ----
    {
        f4* a4 = (f4*)sAll;
        const f4 bpad = {EPSS, EPSS, EPSS, EPSS};
        const f4 ppad = {EPSV, EPSV, EPSV, EPSV};
        for (int i = tid; i < 2527; i += 256) a4[i] = (i < 361) ? bpad : ppad;
    }
    __syncthreads();

    // ---- stage slice z (always real: z in [0,32)) ----
    const int hh = tid >> 3;           // 0..31
    const int j4 = (tid & 7) << 2;     // 0,4,...,28
    {
        const float* bsrc = batch + ((size_t)b * 32 + z) * 1024 + hh * 32 + j4;
        const float* psrc = preds + ((size_t)b * 6 * 32 + z) * 1024 + hh * 32 + j4;
        f4 v = *(const f4*)bsrc;
        v *= SSCL;
        float* dst = sAll + (hh + 3) * LS + (j4 + 3);
        dst[0] = v.x; dst[1] = v.y; dst[2] = v.z; dst[3] = v.w;
        #pragma unroll
        for (int p = 0; p < 6; ++p) {
            f4 w = *(const f4*)(psrc + (size_t)p * 32768);
            float* dq = sAll + (p + 1) * PLANE + (hh + 3) * LS + (j4 + 3);
            dq[0] = w.x; dq[1] = w.y; dq[2] = w.z; dq[3] = w.w;
        }
    }

    const int h = hh, v0 = j4;
    f4 Ip0 = *(const f4*)&batch[((size_t)b * 32 + dl0) * 1024 + h * 32 + v0];
    f4 Ip1 = *(const f4*)&batch[((size_t)b * 32 + dl1) * 1024 + h * 32 + v0];
    Ip0 *= SSCL; Ip1 *= SSCL;

    __syncthreads();

    f4 wsum0 = {}, wsum1 = {};
    f4 acc0[6] = {}, acc1[6] = {};

    #pragma unroll
    for (int dy = 0; dy < 7; ++dy) {
        const int oy = dy - 3;
        const int cyy = oy * oy;                        // compile-time
        const bool act0 = (czz0 + cyy < 16) && !(oz0 == 0 && oy < 0);  // scalar
        const bool act1 = (czz1 + cyy < 16);                           // scalar

        const int rowOff = (h + dy) * LS + v0;          // even -> 8B aligned
        const f2* base = (const f2*)(sAll + rowOff);

        // bseg + pseg(k=0) issued together
        f2 tb0 = base[0], tb1 = base[1], tb2 = base[2], tb3 = base[3], tb4 = base[4];
        f2 p0 = base[PL2], p1 = base[PL2 + 1], p2 = base[PL2 + 2],
           p3 = base[PL2 + 3], p4 = base[PL2 + 4];
        float bseg[10] = {tb0.x, tb0.y, tb1.x, tb1.y, tb2.x, tb2.y, tb3.x, tb3.y, tb4.x, tb4.y};

        f4 wv0[7] = {}, wv1[7] = {};
        #pragma unroll
        for (int dx = 0; dx < 7; ++dx) {
            const int ox = dx - 3;
            const int cxx = ox * ox;                    // compile-time
            const int cyx = cyy + cxx;
            f4 bv = {bseg[dx], bseg[dx + 1], bseg[dx + 2], bseg[dx + 3]};
            if (act0 && (czz0 + cyx < 16) && !(oz0 == 0 && oy == 0 && ox <= 0)) {
                const float g = (float)(czz0 + cyx) * C3F;
                f4 dI = Ip0 - bv;
                f4 w = exp4((f4){g, g, g, g} - dI * dI);
                wv0[dx] = w; wsum0 += w;
            }
            if (act1 && (czz1 + cyx < 16)) {            // oz1 >= 2: no lex needed
                const float g = (float)(czz1 + cyx) * C3F;
                f4 dI = Ip1 - bv;
                f4 w = exp4((f4){g, g, g, g} - dI * dI);
                wv1[dx] = w; wsum1 += w;
            }
        }

        // k-loop: pseg read ONCE serves both centers; prefetch k+1
        #pragma unroll
        for (int k = 0; k < 6; ++k) {
            f2 n0, n1, n2, n3, n4;
            if (k < 5) {
                const f2* nb = base + (size_t)(k + 2) * PL2;
                n0 = nb[0]; n1 = nb[1]; n2 = nb[2]; n3 = nb[3]; n4 = nb[4];
            }
            float pseg[10] = {p0.x, p0.y, p1.x, p1.y, p2.x, p2.y, p3.x, p3.y, p4.x, p4.y};
            if (act0) {
                f4 a = acc0[k];
                #pragma unroll
                for (int dx = 0; dx < 7; ++dx)
                    a += wv0[dx] * (f4){pseg[dx], pseg[dx + 1], pseg[dx + 2], pseg[dx + 3]};
                acc0[k] = a;
            }
            if (act1) {
                f4 a = acc1[k];
                #pragma unroll
                for (int dx = 0; dx < 7; ++dx)
                    a += wv1[dx] * (f4){pseg[dx], pseg[dx + 1], pseg[dx + 2], pseg[dx + 3]};
                acc1[k] = a;
            }
            if (k < 5) { p0 = n0; p1 = n1; p2 = n2; p3 = n3; p4 = n4; }
        }
    }

    // ---- per-center epilogue ----
    float pA[2][6], pV[2][6];
    #pragma unroll
    for (int c = 0; c < 2; ++c) {
        const int ozc = c ? oz1 : oz0;
        const int dcv = c ? d1 : d0;
        const int dlc = c ? dl1 : dl0;
        const int czz = ozc * ozc;
        f4 Ip   = c ? Ip1 : Ip0;
        f4 wsum = c ? wsum1 : wsum0;
        f4* acc = c ? acc1 : acc0;

        // S: reverse-direction pad dist sum (o in H(ozc), p-o outside grid)
        f4 S = {};
        if ((dcv < ozc) || (h < 3) || (h > 28) || (v0 == 0) || (v0 == 28)) {
            const float edz = __builtin_amdgcn_exp2f((float)czz * C3F);
            #pragma unroll
            for (int oy = -3; oy <= 3; ++oy) {
                #pragma unroll
                for (int ox = -3; ox <= 3; ++ox) {
                    const int d2c = oy * oy + ox * ox;
                    if (czz + d2c >= 16) continue;                              // scalar
                    if (ozc == 0 && (oy < 0 || (oy == 0 && ox <= 0))) continue; // scalar
                    const float dist = edz * __builtin_exp2f((float)d2c * C3F);
                    const bool sc = (dcv < ozc) || (h < oy) || (h > 31 + oy);
                    #pragma unroll
                    for (int j = 0; j < 4; ++j) {
                        const int xj = v0 + j;
                        bool m = sc;
                        if (ox > 0) m = m || (xj < ox);
                        if (ox < 0) m = m || (xj > 31 + ox);
                        S[j] += m ? dist : 0.0f;
                    }
                }
            }
        }
        // forward-z-pad analytic sum (added ONCE per center, in its oz==0 task)
        if (ozc == 0) {
            float Sz = 0.f;
            #pragma unroll
            for (int ozp = 1; ozp <= 3; ++ozp) {
                if (dcv + ozp >= 32) {                   // scalar runtime
                    #pragma unroll
                    for (int oy = -3; oy <= 3; ++oy) {
                        #pragma unroll
                        for (int ox = -3; ox <= 3; ++ox) {
                            const int d2 = ozp * ozp + oy * oy + ox * ox;
                            if (d2 < 16) Sz += __builtin_exp2f((float)d2 * C3F); // folds
                        }
                    }
                }
            }
            S += (f4){Sz, Sz, Sz, Sz};
        }
        // e(p) = exp2(-(sI - s*eps)^2); fold S into wsum
        f4 dIe = Ip - (f4){EPSS, EPSS, EPSS, EPSS};
        f4 e4v = exp4(-(dIe * dIe));
        wsum += e4v * S;

        #pragma unroll
        for (int k = 0; k < 6; ++k) {
            const size_t pc = (((size_t)b * 6 + k) * 32 + dlc) * 1024 + h * 32 + v0;
            f4 pcv = *(const f4*)&preds[pc];
            float dA = acc[k].x * pcv.x + acc[k].y * pcv.y + acc[k].z * pcv.z + acc[k].w * pcv.w;
            float hA = acc[k].x + acc[k].y + acc[k].z + acc[k].w;
            float dV = wsum.x * pcv.x + wsum.y * pcv.y + wsum.z * pcv.z + wsum.w * pcv.w;
            pA[c][k] = 2.0f * dA;
            pV[c][k] = dV + hA;
            if (ozc == 0) {   // self term
                pA[c][k] += pcv.x * pcv.x + pcv.y * pcv.y + pcv.z * pcv.z + pcv.w * pcv.w;
                pV[c][k] += pcv.x + pcv.y + pcv.z + pcv.w;
            }
        }
    }

    // wave reduction: 24 values
    #pragma unroll
    for (int c = 0; c < 2; ++c)
        #pragma unroll
        for (int k = 0; k < 6; ++k) {
            #pragma unroll
            for (int off = 32; off > 0; off >>= 1) {
                pA[c][k] += __shfl_down(pA[c][k], off);
                pV[c][k] += __shfl_down(pV[c][k], off);
            }
        }
    const int lane = tid & 63, wave = tid >> 6;
    if (lane == 0) {
        #pragma unroll
        for (int c = 0; c < 2; ++c)
            #pragma unroll
            for (int k = 0; k < 6; ++k) {
                redBuf[wave][c * 12 + k]     = pA[c][k];
                redBuf[wave][c * 12 + 6 + k] = pV[c][k];
            }
    }
    __syncthreads();
    if (tid < 24) {
        const int c = tid / 12, r = tid % 12;
        const int dcv = c ? d1 : d0;
        const int ozc = c ? oz1 : oz0;
        if (dcv >= 0) {
            float s = redBuf[0][tid] + redBuf[1][tid] + redBuf[2][tid] + redBuf[3][tid];
            const size_t task = ((size_t)b * 32 + dcv) * 4 + ozc;
            if (r < 6) wsA[task * 6 + r] = s;
            else       wsV[task * 6 + (r - 6)] = s;
        }
    }
}

// Reduce per batch: 128 task slots (d*4+oz), mask d+oz>31 (never written)
__global__ __launch_bounds__(128) void ncut_final(const float* __restrict__ wsA,
                                                  const float* __restrict__ wsV,
                                                  float* __restrict__ out) {
    __shared__ float redBuf[2][12];
    const int b = blockIdx.x;
    const int t = threadIdx.x;            // 0..127
    const int d = t >> 2, oz = t & 3;
    const bool valid = (d + oz <= 31);
    const size_t task = ((size_t)b * 32 + d) * 4 + oz;
    float a[6], v[6];
    #pragma unroll
    for (int k = 0; k < 6; ++k) {
        a[k] = valid ? wsA[task * 6 + k] : 0.0f;
        v[k] = valid ? wsV[task * 6 + k] : 0.0f;
    }
    #pragma unroll
    for (int k = 0; k < 6; ++k) {
        #pragma unroll
        for (int off = 32; off > 0; off >>= 1) {
            a[k] += __shfl_down(a[k], off);
            v[k] += __shfl_down(v[k], off);
        }
    }
    const int lane = t & 63, wave = t >> 6;
    if (lane == 0) {
        #pragma unroll
        for (int k = 0; k < 6; ++k) {
            redBuf[wave][k]     = a[k];
            redBuf[wave][6 + k] = v[k];
        }
    }
    __syncthreads();
    if (t == 0) {
        float s = 0.f;
        #pragma unroll
        for (int k = 0; k < 6; ++k) {
            float sa = redBuf[0][k] + redBuf[1][k];
            float sv = redBuf[0][6 + k] + redBuf[1][6 + k];
            s += sa / sv;
        }
        out[b] = 6.0f - s;
    }
}

extern "C" void kernel_launch(void* const* d_in, const int* in_sizes, int n_in,
                              void* d_out, int out_size, void* d_ws, size_t ws_size,
                              hipStream_t stream) {
    const float* batch = (const float*)d_in[0];   // 8*1*32^3
    const float* preds = (const float*)d_in[1];   // 8*6*32^3
    float* out = (float*)d_out;                   // 8 floats
    float* wsA = (float*)d_ws;                    // 1024 tasks * 6
    float* wsV = wsA + 1024 * 6;

    ncut_main<<<512, 256, 0, stream>>>(batch, preds, wsA, wsV);
    ncut_final<<<8, 128, 0, stream>>>(wsA, wsV, out);
}